// Round 6
// baseline (263.804 us; speedup 1.0000x reference)
//
#include <hip/hip_runtime.h>

// Problem constants (from reference setup_inputs)
#define BB 2
#define CC 2
#define DD 160
#define HH 192
#define WW 224
#define DHW (DD * HH * WW)
#define HW  (HH * WW)

// Locality-oriented decomposition:
//  - each thread: ZT z-ADJACENT voxels (z-corner rows overlap chain-wise -> L1 hits)
//  - each block: full w-row x HT h-rows (y-corner rows overlap across h -> L1 hits)
#define ZT 8                       // z-voxels per thread (adjacent; 160/8=20 tiles)
#define HT 2                       // h-rows per block
#define TPB (WW * HT)              // 448 threads = 7 waves
#define NH (HH / HT)               // 96 h-tiles
#define NZ (DD / ZT)               // 20 z-tiles
#define NBX (NH * NZ)              // 1920 blocks per batch
#define NXCD 8
#define CPX (NBX / NXCD)           // 240 (1920 % 8 == 0 -> bijective swizzle)

typedef float f2v __attribute__((ext_vector_type(2)));

// 8-byte load at a 4-byte-aligned address (packed struct -> legal lowering)
__device__ __forceinline__ f2v load2u(const float* p) {
    struct __attribute__((packed)) S { f2v v; };
    return ((const S*)p)->v;
}

__global__ __launch_bounds__(TPB) void affine_sample_kernel(
    const float* __restrict__ src,   // [B,C,D,H,W]
    const float* __restrict__ mat,   // [B,3,4]
    float* __restrict__ out)         // [B,C,D,H,W]
{
    // XCD-aware chunked swizzle; work-id inner dim = h-tile so same-XCD
    // neighbors share src rows in that XCD's L2.
    int bx  = blockIdx.x;
    int sbx = (bx & (NXCD - 1)) * CPX + (bx >> 3);
    int h2  = sbx % NH;
    int z8  = sbx / NH;
    int b   = blockIdx.y;

    int tid = (int)threadIdx.x;
    int w   = tid % WW;
    int h   = h2 * HT + tid / WW;
    int d0  = z8 * ZT;

    // theta = mat with translation column normalized per-row by (D,H,W)
    const float* m = mat + b * 12;             // uniform -> s_load
    float a00 = m[0], a01 = m[1], a02 = m[2],  a03 = m[3]  * (1.0f / (float)DD);
    float a10 = m[4], a11 = m[5], a12 = m[6],  a13 = m[7]  * (1.0f / (float)HH);
    float a20 = m[8], a21 = m[9], a22 = m[10], a23 = m[11] * (1.0f / (float)WW);

    float xn = -1.0f + (float)w  * (2.0f / (float)(WW - 1));
    float yn = -1.0f + (float)h  * (2.0f / (float)(HH - 1));
    float zn = -1.0f + (float)d0 * (2.0f / (float)(DD - 1));

    // sample coords at z=d0 (align_corners=True unnormalize folded in)
    float ix0 = (a00 * xn + a01 * yn + a02 * zn + a03 + 1.0f) * ((float)(WW - 1) * 0.5f);
    float iy0 = (a10 * xn + a11 * yn + a12 * zn + a13 + 1.0f) * ((float)(HH - 1) * 0.5f);
    float iz0 = (a20 * xn + a21 * yn + a22 * zn + a23 + 1.0f) * ((float)(DD - 1) * 0.5f);

    // per-z-slice deltas (map is affine in z)
    float dzn = 2.0f / (float)(DD - 1);
    float dix = a02 * dzn * ((float)(WW - 1) * 0.5f);
    float diy = a12 * dzn * ((float)(HH - 1) * 0.5f);
    float diz = a22 * dzn * ((float)(DD - 1) * 0.5f);

    const float* s0 = src + (size_t)b * (CC * DHW);  // ch0 base
    const float* s1 = s0 + DHW;                       // ch1 base
    float* o = out + (size_t)b * (CC * DHW) + (d0 * HH + h) * WW + w;

    #pragma unroll
    for (int v = 0; v < ZT; ++v) {
        float ixv = fmaf((float)v, dix, ix0);
        float iyv = fmaf((float)v, diy, iy0);
        float izv = fmaf((float)v, diz, iz0);

        float fx0 = floorf(ixv), fy0 = floorf(iyv), fz0 = floorf(izv);
        float fx = ixv - fx0, fy = iyv - fy0, fz = izv - fz0;
        int x0 = (int)fx0, y0 = (int)fy0, z0 = (int)fz0;
        int x1 = x0 + 1, y1 = y0 + 1, z1 = z0 + 1;

        // 1-D weights with zero-padding validity folded in
        float wx0 = (x0 >= 0 && x0 < WW) ? (1.0f - fx) : 0.0f;
        float wx1 = (x1 >= 0 && x1 < WW) ? fx          : 0.0f;
        float wy0 = (y0 >= 0 && y0 < HH) ? (1.0f - fy) : 0.0f;
        float wy1 = (y1 >= 0 && y1 < HH) ? fy          : 0.0f;
        float wz0 = (z0 >= 0 && z0 < DD) ? (1.0f - fz) : 0.0f;
        float wz1 = (z1 >= 0 && z1 < DD) ? fz          : 0.0f;

        // clamped indices (safe loads); x-pair base covers both x corners
        int xc0 = min(max(x0, 0), WW - 1), xc1 = min(max(x1, 0), WW - 1);
        int yc0 = min(max(y0, 0), HH - 1), yc1 = min(max(y1, 0), HH - 1);
        int zc0 = min(max(z0, 0), DD - 1), zc1 = min(max(z1, 0), DD - 1);

        int xb   = min(xc0, WW - 2);   // in [0, WW-2]
        int sel0 = xc0 - xb;           // 0 or 1
        int sel1 = xc1 - xb;           // 0 or 1

        // clamp-folded x-pair weights
        float q0 = (sel0 ? 0.0f : wx0) + (sel1 ? 0.0f : wx1);
        float q1 = (sel0 ? wx0 : 0.0f) + (sel1 ? wx1 : 0.0f);

        float w00 = wz0 * wy0, w01 = wz0 * wy1;
        float w10 = wz1 * wy0, w11 = wz1 * wy1;

        int zh0 = zc0 * HH, zh1 = zc1 * HH;
        int r0 = (zh0 + yc0) * WW + xb;
        int r1 = (zh0 + yc1) * WW + xb;
        int r2 = (zh1 + yc0) * WW + xb;
        int r3 = (zh1 + yc1) * WW + xb;

        // 8 gathers; z-adjacency across v makes r2/r3 of step v reappear as
        // r0/r1 of step v+1 (same lines, L1-hot) for the common |a22|~1 case.
        f2v pa0 = load2u(s0 + r0);
        f2v pa1 = load2u(s0 + r1);
        f2v pa2 = load2u(s0 + r2);
        f2v pa3 = load2u(s0 + r3);
        f2v pb0 = load2u(s1 + r0);
        f2v pb1 = load2u(s1 + r1);
        f2v pb2 = load2u(s1 + r2);
        f2v pb3 = load2u(s1 + r3);

        float rq00 = w00 * q0, rq01 = w00 * q1;
        float rq10 = w01 * q0, rq11 = w01 * q1;
        float rq20 = w10 * q0, rq21 = w10 * q1;
        float rq30 = w11 * q0, rq31 = w11 * q1;

        float acc0 = rq00 * pa0[0] + rq01 * pa0[1]
                   + rq10 * pa1[0] + rq11 * pa1[1]
                   + rq20 * pa2[0] + rq21 * pa2[1]
                   + rq30 * pa3[0] + rq31 * pa3[1];
        float acc1 = rq00 * pb0[0] + rq01 * pb0[1]
                   + rq10 * pb1[0] + rq11 * pb1[1]
                   + rq20 * pb2[0] + rq21 * pb2[1]
                   + rq30 * pb3[0] + rq31 * pb3[1];

        // lane-consecutive -> 256B fully coalesced stores
        __builtin_nontemporal_store(acc0, o + v * HW);
        __builtin_nontemporal_store(acc1, o + (DHW + v * HW));
    }
}

extern "C" void kernel_launch(void* const* d_in, const int* in_sizes, int n_in,
                              void* d_out, int out_size, void* d_ws, size_t ws_size,
                              hipStream_t stream) {
    const float* src = (const float*)d_in[0];
    const float* mat = (const float*)d_in[1];
    float* out = (float*)d_out;

    dim3 block(TPB);
    dim3 grid(NBX, BB);
    affine_sample_kernel<<<grid, block, 0, stream>>>(src, mat, out);
}

// Round 7
// 260.095 us; speedup vs baseline: 1.0143x; 1.0143x over previous
//
#include <hip/hip_runtime.h>

// Problem constants (from reference setup_inputs)
#define BB 2
#define CC 2
#define DD 160
#define HH 192
#define WW 224
#define DHW (DD * HH * WW)

#define TPB 256
#define NBX (DHW / (TPB * 2))      // 13440 blocks per batch (2 voxels/thread)
#define NXCD 8
#define CPX (NBX / NXCD)           // 1680 (13440 % 8 == 0 -> bijective swizzle)

typedef float f2v __attribute__((ext_vector_type(2)));
typedef float f4v __attribute__((ext_vector_type(4)));

// Forced 16B gather (saddr form). asm guarantees ONE dwordx4 per call —
// the experiment's controlled variable is gather-instruction count.
__device__ __forceinline__ f4v qload(const float* __restrict__ base, int byteoff) {
    f4v r;
    asm volatile("global_load_dwordx4 %0, %1, %2"
                 : "=v"(r) : "v"(byteoff), "s"(base));
    return r;
}

// 8-byte load at 4-byte alignment (fallback path, compiler-managed)
__device__ __forceinline__ f2v load2u(const float* p) {
    struct __attribute__((packed)) S { f2v v; };
    return ((const S*)p)->v;
}

__device__ __forceinline__ f2v vlo(f4v q) { return __builtin_shufflevector(q, q, 0, 1); }
__device__ __forceinline__ f2v vhi(f4v q) { return __builtin_shufflevector(q, q, 2, 3); }

__global__ __launch_bounds__(TPB, 4) void affine_sample_kernel(
    const float* __restrict__ src,   // [B,C,D,H,W]
    const float* __restrict__ mat,   // [B,3,4]
    float* __restrict__ out)         // [B,C,D,H,W]
{
    // XCD-aware chunked swizzle
    int bx  = blockIdx.x;
    int sbx = (bx & (NXCD - 1)) * CPX + (bx >> 3);
    int pid  = sbx * TPB + (int)threadIdx.x;   // w-pair id
    int base = pid * 2;                         // even voxel index
    int b = blockIdx.y;

    int w = base % WW;        // even; pair is (w, w+1), never crosses a row (224 even)
    int t = base / WW;
    int h = t % HH;
    int d = t / HH;

    // theta = mat with translation column normalized per-row by (D,H,W)
    const float* m = mat + b * 12;
    float a00 = m[0], a01 = m[1], a02 = m[2],  a03 = m[3]  * (1.0f / (float)DD);
    float a10 = m[4], a11 = m[5], a12 = m[6],  a13 = m[7]  * (1.0f / (float)HH);
    float a20 = m[8], a21 = m[9], a22 = m[10], a23 = m[11] * (1.0f / (float)WW);

    float xn = -1.0f + (float)w * (2.0f / (float)(WW - 1));
    float yn = -1.0f + (float)h * (2.0f / (float)(HH - 1));
    float zn = -1.0f + (float)d * (2.0f / (float)(DD - 1));

    // sample coords, align_corners=True unnormalize folded in
    float ixA = (a00*xn + a01*yn + a02*zn + a03 + 1.0f) * ((float)(WW-1)*0.5f);
    float iyA = (a10*xn + a11*yn + a12*zn + a13 + 1.0f) * ((float)(HH-1)*0.5f);
    float izA = (a20*xn + a21*yn + a22*zn + a23 + 1.0f) * ((float)(DD-1)*0.5f);
    // per-w-step deltas in index space
    float ixB = ixA + a00;
    float iyB = iyA + a10 * ((float)(HH-1)/(float)(WW-1));
    float izB = izA + a20 * ((float)(DD-1)/(float)(WW-1));

    // ---- voxel A corners / weights (y,z with zero-pad validity folded) ----
    float fy0A = floorf(iyA), fz0A = floorf(izA);
    float fyA = iyA - fy0A,   fzA = izA - fz0A;
    int y0A = (int)fy0A, z0A = (int)fz0A;
    float wy0A = (y0A >= 0   && y0A < HH)     ? 1.0f - fyA : 0.0f;
    float wy1A = (y0A >= -1  && y0A < HH - 1) ? fyA        : 0.0f;
    float wz0A = (z0A >= 0   && z0A < DD)     ? 1.0f - fzA : 0.0f;
    float wz1A = (z0A >= -1  && z0A < DD - 1) ? fzA        : 0.0f;
    int yc0A = min(max(y0A, 0), HH - 1), yc1A = min(max(y0A + 1, 0), HH - 1);
    int zc0A = min(max(z0A, 0), DD - 1), zc1A = min(max(z0A + 1, 0), DD - 1);

    // ---- voxel B corners / weights ----
    float fy0B = floorf(iyB), fz0B = floorf(izB);
    float fyB = iyB - fy0B,   fzB = izB - fz0B;
    int y0B = (int)fy0B, z0B = (int)fz0B;
    float wy0B = (y0B >= 0   && y0B < HH)     ? 1.0f - fyB : 0.0f;
    float wy1B = (y0B >= -1  && y0B < HH - 1) ? fyB        : 0.0f;
    float wz0B = (z0B >= 0   && z0B < DD)     ? 1.0f - fzB : 0.0f;
    float wz1B = (z0B >= -1  && z0B < DD - 1) ? fzB        : 0.0f;
    int yc0B = min(max(y0B, 0), HH - 1), yc1B = min(max(y0B + 1, 0), HH - 1);
    int zc0B = min(max(z0B, 0), DD - 1), zc1B = min(max(z0B + 1, 0), DD - 1);

    // ---- shared x-quad base; hat weights handle ALL x clamp/pad cases ----
    int x0A = (int)floorf(ixA);
    int x0B = (int)floorf(ixB);
    int xbJ = min(max(x0A, 0), WW - 4);          // quad always in-bounds
    float bxj = (float)xbJ;
    float hA0 = fmaxf(0.0f, 1.0f - fabsf(ixA - bxj));
    float hA1 = fmaxf(0.0f, 1.0f - fabsf(ixA - (bxj + 1.0f)));
    float hA2 = fmaxf(0.0f, 1.0f - fabsf(ixA - (bxj + 2.0f)));
    float hA3 = fmaxf(0.0f, 1.0f - fabsf(ixA - (bxj + 3.0f)));
    float hB0 = fmaxf(0.0f, 1.0f - fabsf(ixB - bxj));
    float hB1 = fmaxf(0.0f, 1.0f - fabsf(ixB - (bxj + 1.0f)));
    float hB2 = fmaxf(0.0f, 1.0f - fabsf(ixB - (bxj + 2.0f)));
    float hB3 = fmaxf(0.0f, 1.0f - fabsf(ixB - (bxj + 3.0f)));

    const float* s0 = src + (size_t)b * (CC * DHW);  // ch0 base (SGPR pair)
    const float* s1 = s0 + DHW;                       // ch1 base

    // A's 4 rows, quad-based byte offsets
    int r0 = ((zc0A * HH + yc0A) * WW + xbJ) * 4;
    int r1 = ((zc0A * HH + yc1A) * WW + xbJ) * 4;
    int r2 = ((zc1A * HH + yc0A) * WW + xbJ) * 4;
    int r3 = ((zc1A * HH + yc1A) * WW + xbJ) * 4;

    // ---- 8 forced 16B gathers (2 voxels per instruction) ----
    f4v qa0 = qload(s0, r0), qa1 = qload(s0, r1), qa2 = qload(s0, r2), qa3 = qload(s0, r3);
    f4v qb0 = qload(s1, r0), qb1 = qload(s1, r1), qb2 = qload(s1, r2), qb3 = qload(s1, r3);

    // row weights
    float rwA0 = wz0A * wy0A, rwA1 = wz0A * wy1A, rwA2 = wz1A * wy0A, rwA3 = wz1A * wy1A;
    float rwB0 = wz0B * wy0B, rwB1 = wz0B * wy1B, rwB2 = wz1B * wy0B, rwB3 = wz1B * wy1B;

    // ---- fallback: B's rows differ from A's (~8% of lanes). Masked loads,
    // issued BEFORE the quad drain so latency overlaps; compiler vmcnt
    // accounting stays conservative-correct with asm loads outstanding. ----
    bool neq = (yc0B != yc0A) | (yc1B != yc1A) | (zc0B != zc0A) | (zc1B != zc1A);
    float fb0 = 0.0f, fb1 = 0.0f;
    if (neq) {
        int xbB = min(max(x0B, 0), WW - 2);
        float u0 = fmaxf(0.0f, 1.0f - fabsf(ixB - (float)xbB));
        float u1 = fmaxf(0.0f, 1.0f - fabsf(ixB - (float)(xbB + 1)));
        int e0 = (zc0B * HH + yc0B) * WW + xbB;
        int e1 = (zc0B * HH + yc1B) * WW + xbB;
        int e2 = (zc1B * HH + yc0B) * WW + xbB;
        int e3 = (zc1B * HH + yc1B) * WW + xbB;
        f2v p0 = load2u(s0 + e0), p1 = load2u(s0 + e1), p2 = load2u(s0 + e2), p3 = load2u(s0 + e3);
        f2v g0 = load2u(s1 + e0), g1 = load2u(s1 + e1), g2 = load2u(s1 + e2), g3 = load2u(s1 + e3);
        fb0 = rwB0 * (u0 * p0.x + u1 * p0.y) + rwB1 * (u0 * p1.x + u1 * p1.y)
            + rwB2 * (u0 * p2.x + u1 * p2.y) + rwB3 * (u0 * p3.x + u1 * p3.y);
        fb1 = rwB0 * (u0 * g0.x + u1 * g0.y) + rwB1 * (u0 * g1.x + u1 * g1.y)
            + rwB2 * (u0 * g2.x + u1 * g2.y) + rwB3 * (u0 * g3.x + u1 * g3.y);
    }

    // drain asm gathers; barrier stops consumers hoisting above (rule #18)
    asm volatile("s_waitcnt vmcnt(0)" ::: "memory");
    __builtin_amdgcn_sched_barrier(0);

    // ---- interpolate: f2v form to invite v_pk_fma_f32 ----
    f2v hA01; hA01.x = hA0; hA01.y = hA1;
    f2v hA23; hA23.x = hA2; hA23.y = hA3;
    f2v hB01; hB01.x = hB0; hB01.y = hB1;
    f2v hB23; hB23.x = hB2; hB23.y = hB3;

    f2v mA0a = rwA0 * hA01, mA0b = rwA0 * hA23;
    f2v mA1a = rwA1 * hA01, mA1b = rwA1 * hA23;
    f2v mA2a = rwA2 * hA01, mA2b = rwA2 * hA23;
    f2v mA3a = rwA3 * hA01, mA3b = rwA3 * hA23;
    f2v mB0a = rwB0 * hB01, mB0b = rwB0 * hB23;
    f2v mB1a = rwB1 * hB01, mB1b = rwB1 * hB23;
    f2v mB2a = rwB2 * hB01, mB2b = rwB2 * hB23;
    f2v mB3a = rwB3 * hB01, mB3b = rwB3 * hB23;

    f2v vA0 = mA0a * vlo(qa0) + mA0b * vhi(qa0) + mA1a * vlo(qa1) + mA1b * vhi(qa1)
            + mA2a * vlo(qa2) + mA2b * vhi(qa2) + mA3a * vlo(qa3) + mA3b * vhi(qa3);
    f2v vA1 = mA0a * vlo(qb0) + mA0b * vhi(qb0) + mA1a * vlo(qb1) + mA1b * vhi(qb1)
            + mA2a * vlo(qb2) + mA2b * vhi(qb2) + mA3a * vlo(qb3) + mA3b * vhi(qb3);
    f2v vB0 = mB0a * vlo(qa0) + mB0b * vhi(qa0) + mB1a * vlo(qa1) + mB1b * vhi(qa1)
            + mB2a * vlo(qa2) + mB2b * vhi(qa2) + mB3a * vlo(qa3) + mB3b * vhi(qa3);
    f2v vB1 = mB0a * vlo(qb0) + mB0b * vhi(qb0) + mB1a * vlo(qb1) + mB1b * vhi(qb1)
            + mB2a * vlo(qb2) + mB2b * vhi(qb2) + mB3a * vlo(qb3) + mB3b * vhi(qb3);

    float accA0 = vA0.x + vA0.y;
    float accA1 = vA1.x + vA1.y;
    float accB0 = neq ? fb0 : (vB0.x + vB0.y);
    float accB1 = neq ? fb1 : (vB1.x + vB1.y);

    // paired stores: 1 dwordx2 per channel, lane-contiguous -> 512B coalesced
    float* o = out + (size_t)b * (CC * DHW) + base;
    f2v st0; st0.x = accA0; st0.y = accB0;
    f2v st1; st1.x = accA1; st1.y = accB1;
    __builtin_nontemporal_store(st0, (f2v*)o);
    __builtin_nontemporal_store(st1, (f2v*)(o + DHW));
}

extern "C" void kernel_launch(void* const* d_in, const int* in_sizes, int n_in,
                              void* d_out, int out_size, void* d_ws, size_t ws_size,
                              hipStream_t stream) {
    const float* src = (const float*)d_in[0];
    const float* mat = (const float*)d_in[1];
    float* out = (float*)d_out;

    dim3 block(TPB);
    dim3 grid(NBX, BB);
    affine_sample_kernel<<<grid, block, 0, stream>>>(src, mat, out);
}

// Round 8
// 256.802 us; speedup vs baseline: 1.0273x; 1.0128x over previous
//
#include <hip/hip_runtime.h>

// Problem constants (from reference setup_inputs)
#define BB 2
#define CC 2
#define DD 160
#define HH 192
#define WW 224
#define DHW (DD * HH * WW)
#define HW  (HH * WW)

// R6 structure (verified correct): thread = ZT z-adjacent voxels, block = w-row x HT h-rows.
// NEW vs R6: register z-chaining — step v+1's z0-rows usually equal step v's
// z1-rows; carry them in registers and reload only lanes where the chain
// breaks (exec-masked load -> inactive lanes send no TCP requests).
#define ZT 8                       // z-voxels per thread (adjacent; 160/8=20 tiles)
#define HT 2                       // h-rows per block
#define TPB (WW * HT)              // 448 threads = 7 waves
#define NH (HH / HT)               // 96 h-tiles
#define NZ (DD / ZT)               // 20 z-tiles
#define NBX (NH * NZ)              // 1920 blocks per batch
#define NXCD 8
#define CPX (NBX / NXCD)           // 240 (1920 % 8 == 0 -> bijective swizzle)

typedef float f2v __attribute__((ext_vector_type(2)));

// 8-byte load at a 4-byte-aligned address (packed struct -> legal lowering)
__device__ __forceinline__ f2v load2u(const float* p) {
    struct __attribute__((packed)) S { f2v v; };
    return ((const S*)p)->v;
}

__global__ __launch_bounds__(TPB) void affine_sample_kernel(
    const float* __restrict__ src,   // [B,C,D,H,W]
    const float* __restrict__ mat,   // [B,3,4]
    float* __restrict__ out)         // [B,C,D,H,W]
{
    // XCD-aware chunked swizzle; h-tile inner so same-XCD neighbors share rows
    int bx  = blockIdx.x;
    int sbx = (bx & (NXCD - 1)) * CPX + (bx >> 3);
    int h2  = sbx % NH;
    int z8  = sbx / NH;
    int b   = blockIdx.y;

    int tid = (int)threadIdx.x;
    int w   = tid % WW;
    int h   = h2 * HT + tid / WW;
    int d0  = z8 * ZT;

    // theta = mat with translation column normalized per-row by (D,H,W)
    const float* m = mat + b * 12;             // uniform -> s_load
    float a00 = m[0], a01 = m[1], a02 = m[2],  a03 = m[3]  * (1.0f / (float)DD);
    float a10 = m[4], a11 = m[5], a12 = m[6],  a13 = m[7]  * (1.0f / (float)HH);
    float a20 = m[8], a21 = m[9], a22 = m[10], a23 = m[11] * (1.0f / (float)WW);

    float xn = -1.0f + (float)w  * (2.0f / (float)(WW - 1));
    float yn = -1.0f + (float)h  * (2.0f / (float)(HH - 1));
    float zn = -1.0f + (float)d0 * (2.0f / (float)(DD - 1));

    // sample coords at z=d0 (align_corners=True unnormalize folded in)
    float ix0 = (a00 * xn + a01 * yn + a02 * zn + a03 + 1.0f) * ((float)(WW - 1) * 0.5f);
    float iy0 = (a10 * xn + a11 * yn + a12 * zn + a13 + 1.0f) * ((float)(HH - 1) * 0.5f);
    float iz0 = (a20 * xn + a21 * yn + a22 * zn + a23 + 1.0f) * ((float)(DD - 1) * 0.5f);

    // per-z-slice deltas (map is affine in z)
    float dzn = 2.0f / (float)(DD - 1);
    float dix = a02 * dzn * ((float)(WW - 1) * 0.5f);
    float diy = a12 * dzn * ((float)(HH - 1) * 0.5f);
    float diz = a22 * dzn * ((float)(DD - 1) * 0.5f);

    const float* s0 = src + (size_t)b * (CC * DHW);  // ch0 base
    const float* s1 = s0 + DHW;                       // ch1 base
    float* o = out + (size_t)b * (CC * DHW) + (d0 * HH + h) * WW + w;

    // carried z-chain state: previous step's z1-rows (indices incl. xb, and data)
    int pr2 = -1, pr3 = -1;
    f2v ppa2, ppa3, ppb2, ppb3;
    ppa2 = 0.0f; ppa3 = 0.0f; ppb2 = 0.0f; ppb3 = 0.0f;

    #pragma unroll
    for (int v = 0; v < ZT; ++v) {
        float ixv = fmaf((float)v, dix, ix0);
        float iyv = fmaf((float)v, diy, iy0);
        float izv = fmaf((float)v, diz, iz0);

        float fx0 = floorf(ixv), fy0 = floorf(iyv), fz0 = floorf(izv);
        float fx = ixv - fx0, fy = iyv - fy0, fz = izv - fz0;
        int x0 = (int)fx0, y0 = (int)fy0, z0 = (int)fz0;
        int x1 = x0 + 1, y1 = y0 + 1, z1 = z0 + 1;

        // 1-D weights with zero-padding validity folded in
        float wx0 = (x0 >= 0 && x0 < WW) ? (1.0f - fx) : 0.0f;
        float wx1 = (x1 >= 0 && x1 < WW) ? fx          : 0.0f;
        float wy0 = (y0 >= 0 && y0 < HH) ? (1.0f - fy) : 0.0f;
        float wy1 = (y1 >= 0 && y1 < HH) ? fy          : 0.0f;
        float wz0 = (z0 >= 0 && z0 < DD) ? (1.0f - fz) : 0.0f;
        float wz1 = (z1 >= 0 && z1 < DD) ? fz          : 0.0f;

        // clamped indices (safe loads); x-pair base covers both x corners
        int xc0 = min(max(x0, 0), WW - 1), xc1 = min(max(x1, 0), WW - 1);
        int yc0 = min(max(y0, 0), HH - 1), yc1 = min(max(y1, 0), HH - 1);
        int zc0 = min(max(z0, 0), DD - 1), zc1 = min(max(z1, 0), DD - 1);

        int xb   = min(xc0, WW - 2);   // in [0, WW-2]
        int sel0 = xc0 - xb;           // 0 or 1
        int sel1 = xc1 - xb;           // 0 or 1

        // clamp-folded x-pair weights
        float q0 = (sel0 ? 0.0f : wx0) + (sel1 ? 0.0f : wx1);
        float q1 = (sel0 ? wx0 : 0.0f) + (sel1 ? wx1 : 0.0f);

        float w00 = wz0 * wy0, w01 = wz0 * wy1;
        float w10 = wz1 * wy0, w11 = wz1 * wy1;

        int zh0 = zc0 * HH, zh1 = zc1 * HH;
        int r0 = (zh0 + yc0) * WW + xb;
        int r1 = (zh0 + yc1) * WW + xb;
        int r2 = (zh1 + yc0) * WW + xb;
        int r3 = (zh1 + yc1) * WW + xb;

        // ---- z-chain: z0-rows usually equal previous step's z1-rows.
        // Exact per-lane test (row index includes xb). Lanes that reuse take
        // register copies; only chain-broken lanes issue the 4 loads
        // (exec-masked -> inactive lanes request no bytes from the TCP).
        f2v pa0, pa1, pb0, pb1;
        bool reuse = (r0 == pr2) && (r1 == pr3);
        if (reuse) {
            pa0 = ppa2; pa1 = ppa3; pb0 = ppb2; pb1 = ppb3;
        } else {
            pa0 = load2u(s0 + r0);
            pa1 = load2u(s0 + r1);
            pb0 = load2u(s1 + r0);
            pb1 = load2u(s1 + r1);
        }

        // z1-rows: always loaded (they seed the next step's chain)
        f2v pa2 = load2u(s0 + r2);
        f2v pa3 = load2u(s0 + r3);
        f2v pb2 = load2u(s1 + r2);
        f2v pb3 = load2u(s1 + r3);

        float rq00 = w00 * q0, rq01 = w00 * q1;
        float rq10 = w01 * q0, rq11 = w01 * q1;
        float rq20 = w10 * q0, rq21 = w10 * q1;
        float rq30 = w11 * q0, rq31 = w11 * q1;

        float acc0 = rq00 * pa0[0] + rq01 * pa0[1]
                   + rq10 * pa1[0] + rq11 * pa1[1]
                   + rq20 * pa2[0] + rq21 * pa2[1]
                   + rq30 * pa3[0] + rq31 * pa3[1];
        float acc1 = rq00 * pb0[0] + rq01 * pb0[1]
                   + rq10 * pb1[0] + rq11 * pb1[1]
                   + rq20 * pb2[0] + rq21 * pb2[1]
                   + rq30 * pb3[0] + rq31 * pb3[1];

        // carry the chain
        pr2 = r2; pr3 = r3;
        ppa2 = pa2; ppa3 = pa3; ppb2 = pb2; ppb3 = pb3;

        // lane-consecutive -> 256B fully coalesced stores
        __builtin_nontemporal_store(acc0, o + v * HW);
        __builtin_nontemporal_store(acc1, o + (DHW + v * HW));
    }
}

extern "C" void kernel_launch(void* const* d_in, const int* in_sizes, int n_in,
                              void* d_out, int out_size, void* d_ws, size_t ws_size,
                              hipStream_t stream) {
    const float* src = (const float*)d_in[0];
    const float* mat = (const float*)d_in[1];
    float* out = (float*)d_out;

    dim3 block(TPB);
    dim3 grid(NBX, BB);
    affine_sample_kernel<<<grid, block, 0, stream>>>(src, mat, out);
}

// Round 9
// 254.199 us; speedup vs baseline: 1.0378x; 1.0102x over previous
//
#include <hip/hip_runtime.h>

// Problem constants (from reference setup_inputs)
#define BB 2
#define CC 2
#define DD 160
#define HH 192
#define WW 224
#define DHW (DD * HH * WW)
#define HW  (HH * WW)

// Composite of the session's two validated winners on the best base:
//  - R2/R4 base: 256-thread blocks (even SIMD balance), launch_bounds(256,4),
//    XCD swizzle; replicated best (113.4/113.8 us per dispatch).
//  - R8 mechanism: ZT z-ADJACENT voxels with register z-chaining (step v+1's
//    z0-rows == step v's z1-rows for ~83% of lanes; only broken lanes load).
//  - NEW A/B: plain cached stores (every prior round used nontemporal).
#define ZT 4                        // adjacent z-slices per thread
#define TPB 256
#define CHUNKS (HW / TPB)           // 168 hw-chunks (43008 % 256 == 0)
#define NZT (DD / ZT)               // 40 z-tiles
#define NBX (NZT * CHUNKS)          // 6720 blocks per batch
#define NXCD 8
#define CPX (NBX / NXCD)            // 840 (6720 % 8 == 0 -> bijective swizzle)

typedef float f2v __attribute__((ext_vector_type(2)));

// 8-byte load at a 4-byte-aligned address (packed struct -> legal lowering)
__device__ __forceinline__ f2v load2u(const float* p) {
    struct __attribute__((packed)) S { f2v v; };
    return ((const S*)p)->v;
}

__global__ __launch_bounds__(TPB, 4) void affine_sample_kernel(
    const float* __restrict__ src,   // [B,C,D,H,W]
    const float* __restrict__ mat,   // [B,3,4]
    float* __restrict__ out)         // [B,C,D,H,W]
{
    // XCD-aware chunked swizzle; z-major grouping: one XCD's concurrent
    // blocks cover ~0.4 of an hw-plane x ~8 z-slices (~1 MB slab -> L2-fit).
    int bx  = blockIdx.x;
    int sbx = (bx & (NXCD - 1)) * CPX + (bx >> 3);
    int dtile = sbx / CHUNKS;
    int chunk = sbx % CHUNKS;
    int b   = blockIdx.y;

    int hw  = chunk * TPB + (int)threadIdx.x;
    int w   = hw % WW;
    int h   = hw / WW;
    int d0  = dtile * ZT;

    // theta = mat with translation column normalized per-row by (D,H,W)
    const float* m = mat + b * 12;             // uniform -> s_load
    float a00 = m[0], a01 = m[1], a02 = m[2],  a03 = m[3]  * (1.0f / (float)DD);
    float a10 = m[4], a11 = m[5], a12 = m[6],  a13 = m[7]  * (1.0f / (float)HH);
    float a20 = m[8], a21 = m[9], a22 = m[10], a23 = m[11] * (1.0f / (float)WW);

    float xn = -1.0f + (float)w  * (2.0f / (float)(WW - 1));
    float yn = -1.0f + (float)h  * (2.0f / (float)(HH - 1));
    float zn = -1.0f + (float)d0 * (2.0f / (float)(DD - 1));

    // sample coords at z=d0 (align_corners=True unnormalize folded in)
    float ix0 = (a00 * xn + a01 * yn + a02 * zn + a03 + 1.0f) * ((float)(WW - 1) * 0.5f);
    float iy0 = (a10 * xn + a11 * yn + a12 * zn + a13 + 1.0f) * ((float)(HH - 1) * 0.5f);
    float iz0 = (a20 * xn + a21 * yn + a22 * zn + a23 + 1.0f) * ((float)(DD - 1) * 0.5f);

    // per-z-slice deltas (map is affine in z)
    float dzn = 2.0f / (float)(DD - 1);
    float dix = a02 * dzn * ((float)(WW - 1) * 0.5f);
    float diy = a12 * dzn * ((float)(HH - 1) * 0.5f);
    float diz = a22 * dzn * ((float)(DD - 1) * 0.5f);

    const float* s0 = src + (size_t)b * (CC * DHW);  // ch0 base
    const float* s1 = s0 + DHW;                       // ch1 base
    float* o = out + (size_t)b * (CC * DHW) + (d0 * HH + h) * WW + w;

    // carried z-chain state: previous step's z1-rows (index incl. xb, + data)
    int pr2 = -1, pr3 = -1;
    f2v ppa2, ppa3, ppb2, ppb3;
    ppa2 = 0.0f; ppa3 = 0.0f; ppb2 = 0.0f; ppb3 = 0.0f;

    #pragma unroll
    for (int v = 0; v < ZT; ++v) {
        float ixv = fmaf((float)v, dix, ix0);
        float iyv = fmaf((float)v, diy, iy0);
        float izv = fmaf((float)v, diz, iz0);

        float fx0 = floorf(ixv), fy0 = floorf(iyv), fz0 = floorf(izv);
        float fx = ixv - fx0, fy = iyv - fy0, fz = izv - fz0;
        int x0 = (int)fx0, y0 = (int)fy0, z0 = (int)fz0;
        int x1 = x0 + 1, y1 = y0 + 1, z1 = z0 + 1;

        // 1-D weights with zero-padding validity folded in
        float wx0 = (x0 >= 0 && x0 < WW) ? (1.0f - fx) : 0.0f;
        float wx1 = (x1 >= 0 && x1 < WW) ? fx          : 0.0f;
        float wy0 = (y0 >= 0 && y0 < HH) ? (1.0f - fy) : 0.0f;
        float wy1 = (y1 >= 0 && y1 < HH) ? fy          : 0.0f;
        float wz0 = (z0 >= 0 && z0 < DD) ? (1.0f - fz) : 0.0f;
        float wz1 = (z1 >= 0 && z1 < DD) ? fz          : 0.0f;

        // clamped indices (safe loads); x-pair base covers both x corners
        int xc0 = min(max(x0, 0), WW - 1), xc1 = min(max(x1, 0), WW - 1);
        int yc0 = min(max(y0, 0), HH - 1), yc1 = min(max(y1, 0), HH - 1);
        int zc0 = min(max(z0, 0), DD - 1), zc1 = min(max(z1, 0), DD - 1);

        int xb   = min(xc0, WW - 2);   // in [0, WW-2]
        int sel0 = xc0 - xb;           // 0 or 1
        int sel1 = xc1 - xb;           // 0 or 1

        // clamp-folded x-pair weights
        float q0 = (sel0 ? 0.0f : wx0) + (sel1 ? 0.0f : wx1);
        float q1 = (sel0 ? wx0 : 0.0f) + (sel1 ? wx1 : 0.0f);

        float w00 = wz0 * wy0, w01 = wz0 * wy1;
        float w10 = wz1 * wy0, w11 = wz1 * wy1;

        int zh0 = zc0 * HH, zh1 = zc1 * HH;
        int r0 = (zh0 + yc0) * WW + xb;
        int r1 = (zh0 + yc1) * WW + xb;
        int r2 = (zh1 + yc0) * WW + xb;
        int r3 = (zh1 + yc1) * WW + xb;

        // z-chain: exact per-lane reuse test (row index includes xb).
        // Reusing lanes take register copies; only chain-broken lanes issue
        // the 4 z0-row loads (exec-masked -> inactive lanes request nothing).
        f2v pa0, pa1, pb0, pb1;
        bool reuse = (r0 == pr2) && (r1 == pr3);
        if (reuse) {
            pa0 = ppa2; pa1 = ppa3; pb0 = ppb2; pb1 = ppb3;
        } else {
            pa0 = load2u(s0 + r0);
            pa1 = load2u(s0 + r1);
            pb0 = load2u(s1 + r0);
            pb1 = load2u(s1 + r1);
        }

        // z1-rows: always loaded (they seed the next step's chain)
        f2v pa2 = load2u(s0 + r2);
        f2v pa3 = load2u(s0 + r3);
        f2v pb2 = load2u(s1 + r2);
        f2v pb3 = load2u(s1 + r3);

        float rq00 = w00 * q0, rq01 = w00 * q1;
        float rq10 = w01 * q0, rq11 = w01 * q1;
        float rq20 = w10 * q0, rq21 = w10 * q1;
        float rq30 = w11 * q0, rq31 = w11 * q1;

        float acc0 = rq00 * pa0[0] + rq01 * pa0[1]
                   + rq10 * pa1[0] + rq11 * pa1[1]
                   + rq20 * pa2[0] + rq21 * pa2[1]
                   + rq30 * pa3[0] + rq31 * pa3[1];
        float acc1 = rq00 * pb0[0] + rq01 * pb0[1]
                   + rq10 * pb1[0] + rq11 * pb1[1]
                   + rq20 * pb2[0] + rq21 * pb2[1]
                   + rq30 * pb3[0] + rq31 * pb3[1];

        // carry the chain
        pr2 = r2; pr3 = r3;
        ppa2 = pa2; ppa3 = pa3; ppb2 = pb2; ppb3 = pb3;

        // A/B vs all prior rounds: PLAIN cached stores (L2 write-back
        // aggregation) instead of nontemporal HBM-direct stores.
        o[v * HW]        = acc0;     // 256B coalesced per wave
        o[DHW + v * HW]  = acc1;
    }
}

extern "C" void kernel_launch(void* const* d_in, const int* in_sizes, int n_in,
                              void* d_out, int out_size, void* d_ws, size_t ws_size,
                              hipStream_t stream) {
    const float* src = (const float*)d_in[0];
    const float* mat = (const float*)d_in[1];
    float* out = (float*)d_out;

    dim3 block(TPB);
    dim3 grid(NBX, BB);
    affine_sample_kernel<<<grid, block, 0, stream>>>(src, mat, out);
}